// Round 2
// baseline (462.120 us; speedup 1.0000x reference)
//
#include <hip/hip_runtime.h>
#include <hip/hip_bf16.h>
#include <stdint.h>

// EdgeModel: out = relu(concat(ek, vrk, vsk, u[batch]) @ W1 + b1) @ W2 + b2
// E=320000, IN_CH=384, HID=128, TGT=64. Inputs/outputs FLOAT32 (per reference);
// compute in bf16 MFMA (2% relative threshold allows it).
//
// Pre-kernel: transpose + cast W1[384][128]f32 -> w1t[128][384]bf16,
//             W2[128][64]f32 -> w2t[64][128]bf16 in d_ws, so W staging can use
//             global_load_lds width=16 (wave-uniform LDS base + lane*16; XOR-16B
//             chunk swizzle applied on the GLOBAL address side).
// Main: 128 edges/block, K in 6 chunks of 64 (chunk = one source tensor).
//   x chunk: manual f32->bf16 staging (8 coalesced float4 loads/thread -> cvt
//            -> 8B ds_write into the same XOR-swizzled layout).
//   GEMM1 -> h^T in C-layout; bias+relu+cvt packs 4 consecutive hid into one
//   8B LDS write of row-major (swizzled) h. GEMM2 -> out^T frags; store f32 16B.

typedef __bf16 bf16;
typedef __attribute__((ext_vector_type(8))) __bf16 bf16x8;
typedef __attribute__((ext_vector_type(4))) __bf16 bf16x4;
typedef __attribute__((ext_vector_type(4))) float floatx4;

__device__ __forceinline__ void ldg2lds16(const void* g, void* l) {
  __builtin_amdgcn_global_load_lds((__attribute__((address_space(1))) void*)g,
                                   (__attribute__((address_space(3))) void*)l,
                                   16, 0, 0);
}

__device__ __forceinline__ bf16x4 cvt_b4(floatx4 v) {
  bf16x4 r; r.x = (bf16)v.x; r.y = (bf16)v.y; r.z = (bf16)v.z; r.w = (bf16)v.w; return r;
}

// ---- pre-kernel: transpose + f32->bf16 cast of the weights into d_ws
__global__ void transpose_pre(const float* __restrict__ w1, bf16* __restrict__ w1t,
                              const float* __restrict__ w2, bf16* __restrict__ w2t) {
  __shared__ float t[32][33];
  int b = blockIdx.x;
  const float* src; bf16* dst; int R, C, tr, tc;
  if (b < 48) { src = w1; dst = w1t; R = 384; C = 128; tr = b >> 2; tc = b & 3; }
  else        { int bb = b - 48; src = w2; dst = w2t; R = 128; C = 64; tr = bb >> 1; tc = bb & 1; }
  int tx = threadIdx.x & 31, ty = threadIdx.x >> 5;   // ty 0..7
  #pragma unroll
  for (int i = 0; i < 32; i += 8)
    t[ty + i][tx] = src[(tr * 32 + ty + i) * C + tc * 32 + tx];
  __syncthreads();
  #pragma unroll
  for (int i = 0; i < 32; i += 8)
    dst[(tc * 32 + ty + i) * R + tr * 32 + tx] = (bf16)t[tx][ty + i];
}

// 48 KB LDS -> 3 blocks/CU
__global__ __launch_bounds__(256, 3) void edge_mlp(
    const float* __restrict__ ek, const float* __restrict__ vrk, const float* __restrict__ vsk,
    const float* __restrict__ u, const int* __restrict__ batch,
    const bf16* __restrict__ w1t, const float* __restrict__ b1,
    const bf16* __restrict__ w2t, const float* __restrict__ b2,
    float* __restrict__ out)
{
  __shared__ __align__(16) bf16 smem[24576];  // 48 KB
  bf16* x_lds  = smem;             // [128 edge][64 k]  swizzled, 16 KB
  bf16* w1_lds = smem + 8192;      // [128 hid ][64 k]  swizzled, 16 KB
  bf16* h_lds  = smem;             // [128 edge][128 k] swizzled, 32 KB (aliases x+w1)
  bf16* w2_lds = smem + 16384;     // [64 tgt ][128 k]  swizzled, 16 KB

  const int tid  = threadIdx.x;
  const int lane = tid & 63;
  const int wv   = tid >> 6;       // wave 0..3
  const int m    = lane & 15;
  const int q    = lane >> 4;
  const int e0   = blockIdx.x * 128;

  const int hid_half  = (wv & 1) * 64;   // GEMM1 2x2 wave grid
  const int edge_half = (wv >> 1) * 64;

  // w1 staging lane constants (global_load_lds: LDS side is lane-fixed)
  const int srow8 = lane >> 3;           // row within 8-row group
  const int sc8   = (lane & 7) ^ srow8;  // logical 16B chunk for this lane

  // ---- stage w2t (bf16) once via global_load_lds, XOR-16 swizzle
  {
    const int r16 = lane >> 4;
    const int c16 = lane & 15;
    #pragma unroll
    for (int i = 0; i < 4; ++i) {
      int j = wv * 4 + i;
      int row = j * 4 + r16;                  // tgt 0..63
      int clog = c16 ^ (row & 15);
      ldg2lds16(w2t + row * 128 + clog * 8, w2_lds + j * 512);
    }
  }

  // ---- bias preloads (f32, 16B each)
  floatx4 bias1[4], bias2[2];
  #pragma unroll
  for (int hf = 0; hf < 4; ++hf)
    bias1[hf] = *(const floatx4*)(b1 + hid_half + hf * 16 + q * 4);
  const int tgt_half = (wv & 1) * 32;
  #pragma unroll
  for (int tf = 0; tf < 2; ++tf)
    bias2[tf] = *(const floatx4*)(b2 + tgt_half + tf * 16 + q * 4);

  // ---- GEMM1: h^T[hid][edge] = sum_k W1t[hid][k] * x[edge][k]
  floatx4 acc[4][4] = {};

  #pragma unroll
  for (int kc = 0; kc < 6; ++kc) {
    // W1t chunk via async 16B direct-to-LDS (bf16 source in d_ws)
    #pragma unroll
    for (int i = 0; i < 4; ++i) {
      int r0  = wv * 32 + i * 8;
      int row = r0 + srow8;
      ldg2lds16(w1t + (long)row * 384 + kc * 64 + sc8 * 8, w1_lds + r0 * 64);
    }
    // x chunk: manual f32 load -> bf16 -> swizzled LDS (2048 float4 / block)
    #pragma unroll
    for (int j = 0; j < 8; ++j) {
      int f = tid + 256 * j;
      int r = f >> 4, c = f & 15;          // edge row, float4-within-row
      const float* srcp;
      if (kc == 0)      srcp = ek  + (long)(e0 + r) * 64;
      else if (kc == 1) srcp = vrk + (long)(e0 + r) * 128;
      else if (kc == 2) srcp = vrk + (long)(e0 + r) * 128 + 64;
      else if (kc == 3) srcp = vsk + (long)(e0 + r) * 128;
      else if (kc == 4) srcp = vsk + (long)(e0 + r) * 128 + 64;
      else              srcp = u   + (long)batch[e0 + r] * 64;
      floatx4 v = *(const floatx4*)(srcp + c * 4);
      int phys = (c >> 1) ^ (r & 7);       // 16B-chunk XOR swizzle
      *(bf16x4*)(x_lds + r * 64 + phys * 8 + (c & 1) * 4) = cvt_b4(v);
    }
    __syncthreads();
    #pragma unroll
    for (int ks = 0; ks < 2; ++ks) {
      bf16x8 af[4], bff[4];
      #pragma unroll
      for (int hf = 0; hf < 4; ++hf) {
        int hid  = hid_half + hf * 16 + m;
        int phys = (ks * 4 + q) ^ (hid & 7);
        af[hf] = *(const bf16x8*)(w1_lds + hid * 64 + phys * 8);
      }
      #pragma unroll
      for (int ef = 0; ef < 4; ++ef) {
        int edge = edge_half + ef * 16 + m;
        int phys = (ks * 4 + q) ^ (edge & 7);
        bff[ef] = *(const bf16x8*)(x_lds + edge * 64 + phys * 8);
      }
      #pragma unroll
      for (int hf = 0; hf < 4; ++hf)
        #pragma unroll
        for (int ef = 0; ef < 4; ++ef)
          acc[hf][ef] = __builtin_amdgcn_mfma_f32_16x16x32_bf16(af[hf], bff[ef], acc[hf][ef], 0, 0, 0);
    }
    __syncthreads();   // reads done before next staging / h_lds alias reuse
  }

  // ---- epilogue 1: bias+relu+bf16; lane's 4 consecutive hid -> one 8B LDS write
  #pragma unroll
  for (int hf = 0; hf < 4; ++hf) {
    int hid0 = hid_half + hf * 16 + q * 4;
    #pragma unroll
    for (int ef = 0; ef < 4; ++ef) {
      int edge = edge_half + ef * 16 + m;
      floatx4 v = acc[hf][ef] + bias1[hf];
      v.x = v.x > 0.f ? v.x : 0.f;
      v.y = v.y > 0.f ? v.y : 0.f;
      v.z = v.z > 0.f ? v.z : 0.f;
      v.w = v.w > 0.f ? v.w : 0.f;
      int c    = hid0 >> 3;
      int phys = c ^ (edge & 15);
      *(bf16x4*)(h_lds + edge * 128 + phys * 8 + (hid0 & 7)) = cvt_b4(v);
    }
  }
  __syncthreads();

  // ---- GEMM2: out^T[tgt][edge] = sum_k W2t[tgt][k] * h[edge][k]
  floatx4 acc2[2][4] = {};
  #pragma unroll
  for (int ks = 0; ks < 4; ++ks) {
    bf16x8 a2[2], bh[4];
    #pragma unroll
    for (int tf = 0; tf < 2; ++tf) {
      int tg   = tgt_half + tf * 16 + m;
      int phys = (ks * 4 + q) ^ (tg & 15);
      a2[tf] = *(const bf16x8*)(w2_lds + tg * 128 + phys * 8);
    }
    #pragma unroll
    for (int ef = 0; ef < 4; ++ef) {
      int ed   = edge_half + ef * 16 + m;
      int phys = (ks * 4 + q) ^ (ed & 15);
      bh[ef] = *(const bf16x8*)(h_lds + ed * 128 + phys * 8);
    }
    #pragma unroll
    for (int tf = 0; tf < 2; ++tf)
      #pragma unroll
      for (int ef = 0; ef < 4; ++ef)
        acc2[tf][ef] = __builtin_amdgcn_mfma_f32_16x16x32_bf16(a2[tf], bh[ef], acc2[tf][ef], 0, 0, 0);
  }

  // ---- store f32: lane's 4 consecutive tgt at fixed edge -> 16B dwordx4
  #pragma unroll
  for (int tf = 0; tf < 2; ++tf) {
    int tgt0 = tgt_half + tf * 16 + q * 4;
    #pragma unroll
    for (int ef = 0; ef < 4; ++ef) {
      int ed = edge_half + ef * 16 + m;
      floatx4 v = acc2[tf][ef] + bias2[tf];
      *(floatx4*)(out + (long)(e0 + ed) * 64 + tgt0) = v;
    }
  }
}

extern "C" void kernel_launch(void* const* d_in, const int* in_sizes, int n_in,
                              void* d_out, int out_size, void* d_ws, size_t ws_size,
                              hipStream_t stream) {
  const float* ek    = (const float*)d_in[0];
  const float* vrk   = (const float*)d_in[1];
  const float* vsk   = (const float*)d_in[2];
  const float* u     = (const float*)d_in[3];
  const int*   batch = (const int*)d_in[4];
  const float* W1    = (const float*)d_in[5];
  const float* b1    = (const float*)d_in[6];
  const float* W2    = (const float*)d_in[7];
  const float* b2    = (const float*)d_in[8];
  float* out = (float*)d_out;

  bf16* w1t = (bf16*)d_ws;               // 128*384 bf16 = 96 KB
  bf16* w2t = (bf16*)d_ws + 128 * 384;   // 64*128 bf16 = 16 KB

  transpose_pre<<<56, 256, 0, stream>>>(W1, w1t, W2, w2t);
  edge_mlp<<<2500, 256, 0, stream>>>(ek, vrk, vsk, u, batch, w1t, b1, w2t, b2, out);
}